// Round 6
// baseline (1824.466 us; speedup 1.0000x reference)
//
#include <hip/hip_runtime.h>
#include <cstddef>

constexpr int NODES = 100000;
constexpr int NPB   = 64;                      // nodes per bucket
constexpr int NBUCK = (NODES + NPB - 1) / NPB; // 1563
constexpr int NREP  = 8;                       // per-XCD-class cursor replicas
constexpr int NB2   = NBUCK * NREP;            // 12504

typedef unsigned long long u64;
typedef __attribute__((ext_vector_type(8)))  _Float16 f16x8;
typedef __attribute__((ext_vector_type(16))) float    f32x16;

__device__ __forceinline__ int rfl_i(int x) {
    return __builtin_amdgcn_readfirstlane(x);
}

// ---- pass 1: histogram. MUST use the exact edge->block mapping of scatter_perm_x ----
__global__ __launch_bounds__(256) void count16(
    const int* __restrict__ idx, int* __restrict__ bcnt, int E)
{
    int* bc = bcnt + (blockIdx.x & (NREP - 1)) * NBUCK;
    const int l = threadIdx.x & 63;
    const int g = l >> 2, q = l & 3;
    int wid = (blockIdx.x * blockDim.x + threadIdx.x) >> 6;
    int nw  = (gridDim.x * blockDim.x) >> 6;
    for (int base = wid * 16; base < E; base += nw * 16) {
        int e = base + g;
        if (e < E && q == 0) atomicAdd(&bc[idx[e] >> 6], 1);
    }
}

// ---- pass 2: single-block exclusive scan (4 elems/thread/round), generic N ----
__global__ __launch_bounds__(1024) void scan4(
    const int* __restrict__ cnt, int* __restrict__ starts, int* __restrict__ cur, int N)
{
    __shared__ int wsum[16];
    __shared__ int running_s;
    int tid = threadIdx.x, lane = tid & 63, wv = tid >> 6;
    if (tid == 0) running_s = 0;
    __syncthreads();
    for (int base = 0; base < N; base += 4096) {
        int i0 = base + tid * 4;
        int c0 = 0, c1 = 0, c2 = 0, c3 = 0;
        if (i0 + 3 < N) {
            int4 c = *(const int4*)(cnt + i0);
            c0 = c.x; c1 = c.y; c2 = c.z; c3 = c.w;
        } else {
            if (i0     < N) c0 = cnt[i0];
            if (i0 + 1 < N) c1 = cnt[i0 + 1];
            if (i0 + 2 < N) c2 = cnt[i0 + 2];
            if (i0 + 3 < N) c3 = cnt[i0 + 3];
        }
        int t = c0 + c1 + c2 + c3;
        int x = t;
        #pragma unroll
        for (int d = 1; d < 64; d <<= 1) {
            int v = __shfl_up(x, d);
            if (lane >= d) x += v;
        }
        if (lane == 63) wsum[wv] = x;
        __syncthreads();
        if (wv == 0 && lane < 16) {
            int y = wsum[lane];
            #pragma unroll
            for (int d = 1; d < 16; d <<= 1) {
                int v = __shfl_up(y, d);
                if (lane >= d) y += v;
            }
            wsum[lane] = y;
        }
        __syncthreads();
        int woff = (wv > 0) ? wsum[wv - 1] : 0;
        int r = running_s;
        int excl = r + woff + (x - t);
        int s0 = excl, s1 = excl + c0, s2 = s1 + c1, s3 = s2 + c2;
        if (i0     < N) { starts[i0]     = s0; cur[i0]     = s0; }
        if (i0 + 1 < N) { starts[i0 + 1] = s1; cur[i0 + 1] = s1; }
        if (i0 + 2 < N) { starts[i0 + 2] = s2; cur[i0 + 2] = s2; }
        if (i0 + 3 < N) { starts[i0 + 3] = s3; cur[i0 + 3] = s3; }
        int total = wsum[15];
        __syncthreads();
        if (tid == 0) running_s = r + total;
    }
    __syncthreads();
    if (tid == 0) starts[N] = running_s;
}

// ---- pass 3: permute w-premultiplied rows into bucket order ----
// rep = blockIdx&7 (round-robin => XCD-local appends, no dirty-line bouncing).
// nloc (6b) embedded in mantissa LSBs of row word 0.
__global__ __launch_bounds__(256) void scatter_perm_x(
    const float4* __restrict__ cf4, const float* __restrict__ wts,
    const int* __restrict__ idx, int* __restrict__ bcur,
    float* __restrict__ den, float4* __restrict__ cfs4, int E)
{
    int* cur = bcur + (blockIdx.x & (NREP - 1)) * NBUCK;
    const int l = threadIdx.x & 63;
    const int g = l >> 2, q = l & 3;             // 16 edges per wave-iter
    int wid = (blockIdx.x * blockDim.x + threadIdx.x) >> 6;
    int nw  = (gridDim.x * blockDim.x) >> 6;
    for (int base = wid * 16; base < E; base += nw * 16) {
        int e = base + g;
        bool valid = e < E;
        float4 v = {0.f, 0.f, 0.f, 0.f};
        float w = 0.f;
        int slot = 0, nloc = 0;
        if (valid) {
            v = cf4[(size_t)e * 4 + q];
            w = wts[e];
            if (q == 0) {
                int n = idx[e];
                nloc = n & 63;
                slot = atomicAdd(&cur[n >> 6], 1);
                unsafeAtomicAdd(&den[n], w);
            }
        }
        slot = __shfl(slot, l & ~3);
        if (valid) {
            v.x *= w; v.y *= w; v.z *= w; v.w *= w;
            if (q == 0) {
                unsigned bits = (__float_as_uint(v.x) & ~63u) | (unsigned)nloc;
                v.x = __uint_as_float(bits);
            }
            cfs4[(size_t)slot * 4 + q] = v;       // 4 lanes = one full 64B block
        }
    }
}

// ---- pass 4: stream sorted rows sequentially, MFMA, LDS-accumulate, divide ----
// MFMA 32x32x16 f16 mappings verified by round 5 (passed absmax):
//   A: lane supplies A[row=l&31][k=8*(l>>5)+j]
//   B: lane supplies B[k=8*(l>>5)+j][n=l&31]  (emb^T)
//   D: col=lane&31, row=(reg&3)+8*(reg>>2)+4*(lane>>5)
__global__ __launch_bounds__(256) void gather_stream_mfma(
    const float* __restrict__ emb, const float4* __restrict__ cfs4,
    const int* __restrict__ bstarts, const float* __restrict__ den,
    float* __restrict__ out)
{
    __shared__ float num[NPB * 64];              // 16 KB
    __shared__ __align__(16) int nlbuf[4][64];
    __shared__ float dls[NPB];

    const int tid = threadIdx.x;
    const int l   = tid & 63;
    const int wv  = tid >> 6;
    const int b   = blockIdx.x;
    const int ucol = l & 31;
    const int h    = l >> 5;

    const float4 z4 = {0.f, 0.f, 0.f, 0.f};
    for (int i = tid; i < NPB * 16; i += 256) ((float4*)num)[i] = z4;

    f16x8 b0, b1;
    #pragma unroll
    for (int j = 0; j < 8; ++j) {
        b0[j] = (_Float16)emb[ucol * 16 + 8 * h + j];
        b1[j] = (_Float16)emb[(ucol + 32) * 16 + 8 * h + j];
    }
    __syncthreads();

    #pragma unroll 1
    for (int rep = 0; rep < NREP; ++rep) {
        const int rs = rfl_i(bstarts[rep * NBUCK + b]);
        const int re = rfl_i(bstarts[rep * NBUCK + b + 1]);
        for (int base = rs + wv * 64; base < re; base += 256) {
            int rA = base + ucol;           // chunk A: rows [base, base+32)
            int rB = base + 32 + ucol;      // chunk B: rows [base+32, base+64)
            // sequential coalesced loads (buffer has 64-row slack for tails)
            float4 cA0 = cfs4[(size_t)rA * 4 + h * 2];
            float4 cA1 = cfs4[(size_t)rA * 4 + h * 2 + 1];
            float4 cB0 = cfs4[(size_t)rB * 4 + h * 2];
            float4 cB1 = cfs4[(size_t)rB * 4 + h * 2 + 1];
            bool vA = rA < re, vB = rB < re;
            if (!vA) { cA0 = z4; cA1 = z4; }
            if (!vB) { cB0 = z4; cB1 = z4; }
            if (h == 0) {
                nlbuf[wv][ucol]      = vA ? (int)(__float_as_uint(cA0.x) & 63u) : 0;
                nlbuf[wv][32 + ucol] = vB ? (int)(__float_as_uint(cB0.x) & 63u) : 0;
            }
            f16x8 aA, aB;
            aA[0] = (_Float16)cA0.x; aA[1] = (_Float16)cA0.y;
            aA[2] = (_Float16)cA0.z; aA[3] = (_Float16)cA0.w;
            aA[4] = (_Float16)cA1.x; aA[5] = (_Float16)cA1.y;
            aA[6] = (_Float16)cA1.z; aA[7] = (_Float16)cA1.w;
            aB[0] = (_Float16)cB0.x; aB[1] = (_Float16)cB0.y;
            aB[2] = (_Float16)cB0.z; aB[3] = (_Float16)cB0.w;
            aB[4] = (_Float16)cB1.x; aB[5] = (_Float16)cB1.y;
            aB[6] = (_Float16)cB1.z; aB[7] = (_Float16)cB1.w;

            f32x16 zacc;
            #pragma unroll
            for (int i = 0; i < 16; ++i) zacc[i] = 0.f;

            f32x16 d0 = __builtin_amdgcn_mfma_f32_32x32x16_f16(aA, b0, zacc, 0, 0, 0);
            f32x16 d1 = __builtin_amdgcn_mfma_f32_32x32x16_f16(aA, b1, zacc, 0, 0, 0);
            #pragma unroll
            for (int j = 0; j < 4; ++j) {
                int4 nj = *(const int4*)&nlbuf[wv][8 * j + 4 * h];
                int r0 = 4 * j;
                atomicAdd(&num[nj.x * 64 + ucol],      fmaxf(d0[r0 + 0], 0.f));
                atomicAdd(&num[nj.x * 64 + 32 + ucol], fmaxf(d1[r0 + 0], 0.f));
                atomicAdd(&num[nj.y * 64 + ucol],      fmaxf(d0[r0 + 1], 0.f));
                atomicAdd(&num[nj.y * 64 + 32 + ucol], fmaxf(d1[r0 + 1], 0.f));
                atomicAdd(&num[nj.z * 64 + ucol],      fmaxf(d0[r0 + 2], 0.f));
                atomicAdd(&num[nj.z * 64 + 32 + ucol], fmaxf(d1[r0 + 2], 0.f));
                atomicAdd(&num[nj.w * 64 + ucol],      fmaxf(d0[r0 + 3], 0.f));
                atomicAdd(&num[nj.w * 64 + 32 + ucol], fmaxf(d1[r0 + 3], 0.f));
            }
            f32x16 e0 = __builtin_amdgcn_mfma_f32_32x32x16_f16(aB, b0, zacc, 0, 0, 0);
            f32x16 e1 = __builtin_amdgcn_mfma_f32_32x32x16_f16(aB, b1, zacc, 0, 0, 0);
            #pragma unroll
            for (int j = 0; j < 4; ++j) {
                int4 nj = *(const int4*)&nlbuf[wv][32 + 8 * j + 4 * h];
                int r0 = 4 * j;
                atomicAdd(&num[nj.x * 64 + ucol],      fmaxf(e0[r0 + 0], 0.f));
                atomicAdd(&num[nj.x * 64 + 32 + ucol], fmaxf(e1[r0 + 0], 0.f));
                atomicAdd(&num[nj.y * 64 + ucol],      fmaxf(e0[r0 + 1], 0.f));
                atomicAdd(&num[nj.y * 64 + 32 + ucol], fmaxf(e1[r0 + 1], 0.f));
                atomicAdd(&num[nj.z * 64 + ucol],      fmaxf(e0[r0 + 2], 0.f));
                atomicAdd(&num[nj.z * 64 + 32 + ucol], fmaxf(e1[r0 + 2], 0.f));
                atomicAdd(&num[nj.w * 64 + ucol],      fmaxf(e0[r0 + 3], 0.f));
                atomicAdd(&num[nj.w * 64 + 32 + ucol], fmaxf(e1[r0 + 3], 0.f));
            }
        }
    }
    __syncthreads();

    if (tid < NPB) {
        int node = b * NPB + tid;
        dls[tid] = (node < NODES) ? den[node] : 1.f;
    }
    __syncthreads();

    const int n0 = b * NPB;
    for (int i = tid; i < NPB * 16; i += 256) {
        int nl = i >> 4;
        int node = n0 + nl;
        if (node < NODES) {
            float d = dls[nl];
            float4 v = ((float4*)num)[i];
            v.x /= d; v.y /= d; v.z /= d; v.w /= d;
            ((float4*)(out + (size_t)node * 64))[i & 15] = v;
        }
    }
}

// ================= fallbacks =================

__global__ __launch_bounds__(256) void count_node(
    const int* __restrict__ idx, int* __restrict__ cnt, int E)
{
    int i = blockIdx.x * blockDim.x + threadIdx.x;
    int stride = gridDim.x * blockDim.x;
    for (; i < E; i += stride) atomicAdd(&cnt[idx[i]], 1);
}

__global__ __launch_bounds__(256) void scatter_csr_fb(
    const int* __restrict__ idx, const float* __restrict__ wts,
    int* __restrict__ cursor, int* __restrict__ elist,
    float* __restrict__ welist, int E)
{
    int i = blockIdx.x * blockDim.x + threadIdx.x;
    int stride = gridDim.x * blockDim.x;
    for (; i < E; i += stride) {
        int n = idx[i];
        int slot = atomicAdd(&cursor[n], 1);
        elist[slot]  = i;
        welist[slot] = wts[i];
    }
}

__global__ __launch_bounds__(256) void gather_csr_fb(
    const float* __restrict__ emb, const float* __restrict__ cf,
    const int* __restrict__ starts, const int* __restrict__ elist,
    const float* __restrict__ welist, float* __restrict__ out)
{
    const int lane = threadIdx.x & 63;
    float er[16];
    #pragma unroll
    for (int f = 0; f < 16; ++f) er[f] = emb[lane * 16 + f];
    int gw = rfl_i((int)((blockIdx.x * blockDim.x + threadIdx.x) >> 6));
    int nw = (gridDim.x * blockDim.x) >> 6;
    for (int node = gw; node < NODES; node += nw) {
        int s = rfl_i(starts[node]);
        int e = rfl_i(starts[node + 1]);
        float acc = 0.f, den = 0.f;
        for (int p = s; p < e; ++p) {
            int e0 = rfl_i(elist[p]);
            float w0 = __int_as_float(rfl_i(__float_as_int(welist[p])));
            const float* c0 = cf + (size_t)e0 * 16;
            float a0 = 0.f;
            #pragma unroll
            for (int f = 0; f < 16; ++f) a0 = fmaf(c0[f], er[f], a0);
            acc = fmaf(fmaxf(a0, 0.f), w0, acc);
            den += w0;
        }
        out[(size_t)node * 64 + lane] = acc / den;
    }
}

__global__ __launch_bounds__(256) void edge_scatter_fb(
    const float* __restrict__ emb, const float* __restrict__ cf,
    const float* __restrict__ wts, const int* __restrict__ idx,
    float* __restrict__ num, float* __restrict__ den, int E)
{
    const int lane = threadIdx.x & 63;
    float er[16];
    #pragma unroll
    for (int f = 0; f < 16; ++f) er[f] = emb[lane * 16 + f];
    int wid = rfl_i((int)((blockIdx.x * blockDim.x + threadIdx.x) >> 6));
    int nw = (gridDim.x * blockDim.x) >> 6;
    for (int e = wid; e < E; e += nw) {
        const float* c = cf + (size_t)e * 16;
        float a = 0.f;
        #pragma unroll
        for (int f = 0; f < 16; ++f) a = fmaf(c[f], er[f], a);
        float wv = wts[e];
        int n = idx[e];
        unsafeAtomicAdd(num + (size_t)n * 64 + lane, fmaxf(a, 0.f) * wv);
        if (lane == 0) unsafeAtomicAdd(den + n, wv);
    }
}

__global__ __launch_bounds__(256) void divide_fb(
    float* __restrict__ out, const float* __restrict__ den, int nvec)
{
    int i = blockIdx.x * blockDim.x + threadIdx.x;
    int stride = gridDim.x * blockDim.x;
    float4* o4 = reinterpret_cast<float4*>(out);
    for (; i < nvec; i += stride) {
        float4 v = o4[i];
        float d = den[i >> 4];
        v.x /= d; v.y /= d; v.z /= d; v.w /= d;
        o4[i] = v;
    }
}

extern "C" void kernel_launch(void* const* d_in, const int* in_sizes, int n_in,
                              void* d_out, int out_size, void* d_ws, size_t ws_size,
                              hipStream_t stream)
{
    const float* emb = (const float*)d_in[0];   // (64,16)
    const float* cf  = (const float*)d_in[1];   // (E,16)
    const float* wts = (const float*)d_in[2];   // (E,)
    const int*   idx = (const int*)d_in[3];     // (E,)
    int E = in_sizes[2];
    float* out = (float*)d_out;

    // fast-path ws: bcnt[NB2] | bstarts[NB2+1] | bcur[NB2] | den[NODES] | pad | cfs[(E+64) rows]
    char* wsb = (char*)d_ws;
    int* bcnt    = (int*)wsb;
    int* bstarts = bcnt + NB2;
    int* bcur    = bstarts + NB2 + 1;
    float* den   = (float*)(bcur + NB2);
    size_t off = (size_t)(3 * NB2 + 1 + NODES) * sizeof(int);
    off = (off + 255) & ~(size_t)255;
    float* cfs = (float*)(wsb + off);
    size_t need_big = off + ((size_t)E + 64) * 16 * sizeof(float);

    size_t need_csr = ((size_t)3 * NODES + 2 + 2 * (size_t)E) * sizeof(int);

    if (E < (1 << 22) && ws_size >= need_big) {
        hipMemsetAsync(bcnt, 0, NB2 * sizeof(int), stream);
        hipMemsetAsync(den, 0, NODES * sizeof(float), stream);
        count16<<<4096, 256, 0, stream>>>(idx, bcnt, E);
        scan4<<<1, 1024, 0, stream>>>(bcnt, bstarts, bcur, NB2);
        scatter_perm_x<<<4096, 256, 0, stream>>>(
            (const float4*)cf, wts, idx, bcur, den, (float4*)cfs, E);
        gather_stream_mfma<<<NBUCK, 256, 0, stream>>>(
            emb, (const float4*)cfs, bstarts, den, out);
    } else if (ws_size >= need_csr) {
        int* cnt2      = (int*)d_ws;
        int* starts2   = cnt2 + NODES;
        int* cursor2   = starts2 + NODES + 1;
        int* elist     = cursor2 + NODES;
        float* welist  = (float*)(elist + E);
        hipMemsetAsync(cnt2, 0, NODES * sizeof(int), stream);
        count_node<<<2048, 256, 0, stream>>>(idx, cnt2, E);
        scan4<<<1, 1024, 0, stream>>>(cnt2, starts2, cursor2, NODES);
        scatter_csr_fb<<<2048, 256, 0, stream>>>(idx, wts, cursor2, elist, welist, E);
        gather_csr_fb<<<4096, 256, 0, stream>>>(emb, cf, starts2, elist, welist, out);
    } else {
        float* den2 = (float*)d_ws;
        hipMemsetAsync(d_out, 0, (size_t)out_size * sizeof(float), stream);
        hipMemsetAsync(d_ws, 0, (size_t)NODES * sizeof(float), stream);
        edge_scatter_fb<<<4096, 256, 0, stream>>>(emb, cf, wts, idx, out, den2, E);
        divide_fb<<<2048, 256, 0, stream>>>(out, den2, out_size / 4);
    }
}

// Round 7
// 585.685 us; speedup vs baseline: 3.1151x; 3.1151x over previous
//
#include <hip/hip_runtime.h>
#include <cstddef>

constexpr int NODES = 100000;

typedef __attribute__((ext_vector_type(8)))  _Float16 f16x8;
typedef __attribute__((ext_vector_type(16))) float    f32x16;

__device__ __forceinline__ int rfl_i(int x) {
    return __builtin_amdgcn_readfirstlane(x);
}
__device__ __forceinline__ float rfl_f(float x) {
    return __int_as_float(__builtin_amdgcn_readfirstlane(__float_as_int(x)));
}

// ---- pass 1: per-node histogram (400 KB counter table, L2-resident) ----
__global__ __launch_bounds__(256) void count_node(
    const int* __restrict__ idx, int* __restrict__ cnt, int E)
{
    int i = blockIdx.x * blockDim.x + threadIdx.x;
    int stride = gridDim.x * blockDim.x;
    int e4 = E >> 2;
    const int4* idx4 = (const int4*)idx;
    for (int j = i; j < e4; j += stride) {
        int4 v = idx4[j];
        atomicAdd(&cnt[v.x], 1); atomicAdd(&cnt[v.y], 1);
        atomicAdd(&cnt[v.z], 1); atomicAdd(&cnt[v.w], 1);
    }
    for (int j = (e4 << 2) + i; j < E; j += stride) atomicAdd(&cnt[idx[j]], 1);
}

// ---- pass 2: single-block exclusive scan (4 elems/thread/round) ----
__global__ __launch_bounds__(1024) void scan4(
    const int* __restrict__ cnt, int* __restrict__ starts, int* __restrict__ cur, int N)
{
    __shared__ int wsum[16];
    __shared__ int running_s;
    int tid = threadIdx.x, lane = tid & 63, wv = tid >> 6;
    if (tid == 0) running_s = 0;
    __syncthreads();
    for (int base = 0; base < N; base += 4096) {
        int i0 = base + tid * 4;
        int c0 = 0, c1 = 0, c2 = 0, c3 = 0;
        if (i0 + 3 < N) {
            int4 c = *(const int4*)(cnt + i0);
            c0 = c.x; c1 = c.y; c2 = c.z; c3 = c.w;
        } else {
            if (i0     < N) c0 = cnt[i0];
            if (i0 + 1 < N) c1 = cnt[i0 + 1];
            if (i0 + 2 < N) c2 = cnt[i0 + 2];
            if (i0 + 3 < N) c3 = cnt[i0 + 3];
        }
        int t = c0 + c1 + c2 + c3;
        int x = t;
        #pragma unroll
        for (int d = 1; d < 64; d <<= 1) {
            int v = __shfl_up(x, d);
            if (lane >= d) x += v;
        }
        if (lane == 63) wsum[wv] = x;
        __syncthreads();
        if (wv == 0 && lane < 16) {
            int y = wsum[lane];
            #pragma unroll
            for (int d = 1; d < 16; d <<= 1) {
                int v = __shfl_up(y, d);
                if (lane >= d) y += v;
            }
            wsum[lane] = y;
        }
        __syncthreads();
        int woff = (wv > 0) ? wsum[wv - 1] : 0;
        int r = running_s;
        int excl = r + woff + (x - t);
        int s0 = excl, s1 = excl + c0, s2 = s1 + c1, s3 = s2 + c2;
        if (i0     < N) { starts[i0]     = s0; cur[i0]     = s0; }
        if (i0 + 1 < N) { starts[i0 + 1] = s1; cur[i0 + 1] = s1; }
        if (i0 + 2 < N) { starts[i0 + 2] = s2; cur[i0 + 2] = s2; }
        if (i0 + 3 < N) { starts[i0 + 3] = s3; cur[i0 + 3] = s3; }
        int total = wsum[15];
        __syncthreads();
        if (tid == 0) running_s = r + total;
    }
    __syncthreads();
    if (tid == 0) starts[N] = running_s;
}

// ---- pass 3: permute w-premultiplied rows into node order (full-line stores) ----
// lane l: edge group g=l/4, quarter q=l%4 -> 4 lanes write one 64B row.
__global__ __launch_bounds__(256) void scatter_perm(
    const float4* __restrict__ cf4, const float* __restrict__ wts,
    const int* __restrict__ idx, int* __restrict__ cur,
    float* __restrict__ den, float4* __restrict__ cfs4, int E)
{
    const int l = threadIdx.x & 63;
    const int g = l >> 2, q = l & 3;             // 16 edges per wave-iter
    int wid = (blockIdx.x * blockDim.x + threadIdx.x) >> 6;
    int nw  = (gridDim.x * blockDim.x) >> 6;
    for (int base = wid * 16; base < E; base += nw * 16) {
        int e = base + g;
        bool valid = e < E;
        float4 v = {0.f, 0.f, 0.f, 0.f};
        float w = 0.f;
        int slot = 0;
        if (valid) {
            v = cf4[(size_t)e * 4 + q];
            w = wts[e];
            if (q == 0) {
                int n = idx[e];
                slot = atomicAdd(&cur[n], 1);
                unsafeAtomicAdd(&den[n], w);
            }
        }
        slot = __shfl(slot, l & ~3);
        if (valid) {
            v.x *= w; v.y *= w; v.z *= w; v.w *= w;
            cfs4[(size_t)slot * 4 + q] = v;       // 4 lanes = one full 64B row
        }
    }
}

// ---- pass 4: per-node segment gather. No atomics, no LDS accumulation. ----
// One wave per node; 32-row chunks; MFMA 32x32x16 f16 (mappings verified R5/R6):
//   A: lane(ucol,h) supplies A[row=ucol][k=8h+j]
//   B: lane supplies B[k=8h+j][n=ucol]   (emb^T; b0 = chans 0-31, b1 = 32-63)
//   D: col=lane&31, row=(reg&3)+8*(reg>>2)+4*(lane>>5)
// Row-sum after relu: per-lane sum of 16 regs covers rows of its h-half;
// __shfl_xor(·,32) merges halves. Edge-sum commutes with the chunk reduce.
__global__ __launch_bounds__(256) void gather_seg(
    const float* __restrict__ emb, const float4* __restrict__ cfs4,
    const int* __restrict__ starts, const float* __restrict__ den,
    float* __restrict__ out)
{
    const int tid  = threadIdx.x;
    const int l    = tid & 63;
    const int ucol = l & 31;
    const int h    = l >> 5;

    f16x8 b0, b1;
    #pragma unroll
    for (int j = 0; j < 8; ++j) {
        b0[j] = (_Float16)emb[ucol * 16 + 8 * h + j];
        b1[j] = (_Float16)emb[(ucol + 32) * 16 + 8 * h + j];
    }

    const float4 z4 = {0.f, 0.f, 0.f, 0.f};
    f32x16 zacc;
    #pragma unroll
    for (int i = 0; i < 16; ++i) zacc[i] = 0.f;

    int gw = (blockIdx.x * blockDim.x + threadIdx.x) >> 6;
    int nw = (gridDim.x * blockDim.x) >> 6;

    for (int node = gw; node < NODES; node += nw) {
        int s = rfl_i(starts[node]);
        int e = rfl_i(starts[node + 1]);
        int cnt = e - s;
        float r0 = 0.f, r1 = 0.f;
        for (int ch = 0; ch < cnt; ch += 32) {
            int row = s + ch + ucol;
            bool valid = (ch + ucol) < cnt;       // mask: rows past cnt belong to next node
            // contiguous 2KB span per wave, per-lane coalesced (slack rows at buffer end)
            float4 c0 = cfs4[(size_t)row * 4 + h * 2];
            float4 c1 = cfs4[(size_t)row * 4 + h * 2 + 1];
            if (!valid) { c0 = z4; c1 = z4; }
            f16x8 a;
            a[0] = (_Float16)c0.x; a[1] = (_Float16)c0.y;
            a[2] = (_Float16)c0.z; a[3] = (_Float16)c0.w;
            a[4] = (_Float16)c1.x; a[5] = (_Float16)c1.y;
            a[6] = (_Float16)c1.z; a[7] = (_Float16)c1.w;
            f32x16 d0 = __builtin_amdgcn_mfma_f32_32x32x16_f16(a, b0, zacc, 0, 0, 0);
            f32x16 d1 = __builtin_amdgcn_mfma_f32_32x32x16_f16(a, b1, zacc, 0, 0, 0);
            float t0 = 0.f, t1 = 0.f;
            #pragma unroll
            for (int r = 0; r < 16; ++r) {
                t0 += fmaxf(d0[r], 0.f);
                t1 += fmaxf(d1[r], 0.f);
            }
            r0 += t0; r1 += t1;
        }
        r0 += __shfl_xor(r0, 32);
        r1 += __shfl_xor(r1, 32);
        float d = rfl_f(den[node]);
        float val = (h ? r1 : r0) / d;
        out[(size_t)node * 64 + l] = val;         // coalesced 256B store
    }
}

// ================= fallbacks =================

__global__ __launch_bounds__(256) void scatter_csr_fb(
    const int* __restrict__ idx, const float* __restrict__ wts,
    int* __restrict__ cursor, int* __restrict__ elist,
    float* __restrict__ welist, int E)
{
    int i = blockIdx.x * blockDim.x + threadIdx.x;
    int stride = gridDim.x * blockDim.x;
    for (; i < E; i += stride) {
        int n = idx[i];
        int slot = atomicAdd(&cursor[n], 1);
        elist[slot]  = i;
        welist[slot] = wts[i];
    }
}

__global__ __launch_bounds__(256) void gather_csr_fb(
    const float* __restrict__ emb, const float* __restrict__ cf,
    const int* __restrict__ starts, const int* __restrict__ elist,
    const float* __restrict__ welist, float* __restrict__ out)
{
    const int lane = threadIdx.x & 63;
    float er[16];
    #pragma unroll
    for (int f = 0; f < 16; ++f) er[f] = emb[lane * 16 + f];
    int gw = rfl_i((int)((blockIdx.x * blockDim.x + threadIdx.x) >> 6));
    int nw = (gridDim.x * blockDim.x) >> 6;
    for (int node = gw; node < NODES; node += nw) {
        int s = rfl_i(starts[node]);
        int e = rfl_i(starts[node + 1]);
        float acc = 0.f, den = 0.f;
        for (int p = s; p < e; ++p) {
            int e0 = rfl_i(elist[p]);
            float w0 = rfl_f(welist[p]);
            const float* c0 = cf + (size_t)e0 * 16;
            float a0 = 0.f;
            #pragma unroll
            for (int f = 0; f < 16; ++f) a0 = fmaf(c0[f], er[f], a0);
            acc = fmaf(fmaxf(a0, 0.f), w0, acc);
            den += w0;
        }
        out[(size_t)node * 64 + lane] = acc / den;
    }
}

__global__ __launch_bounds__(256) void edge_scatter_fb(
    const float* __restrict__ emb, const float* __restrict__ cf,
    const float* __restrict__ wts, const int* __restrict__ idx,
    float* __restrict__ num, float* __restrict__ den, int E)
{
    const int lane = threadIdx.x & 63;
    float er[16];
    #pragma unroll
    for (int f = 0; f < 16; ++f) er[f] = emb[lane * 16 + f];
    int wid = rfl_i((int)((blockIdx.x * blockDim.x + threadIdx.x) >> 6));
    int nw = (gridDim.x * blockDim.x) >> 6;
    for (int e = wid; e < E; e += nw) {
        const float* c = cf + (size_t)e * 16;
        float a = 0.f;
        #pragma unroll
        for (int f = 0; f < 16; ++f) a = fmaf(c[f], er[f], a);
        float wv = wts[e];
        int n = idx[e];
        unsafeAtomicAdd(num + (size_t)n * 64 + lane, fmaxf(a, 0.f) * wv);
        if (lane == 0) unsafeAtomicAdd(den + n, wv);
    }
}

__global__ __launch_bounds__(256) void divide_fb(
    float* __restrict__ out, const float* __restrict__ den, int nvec)
{
    int i = blockIdx.x * blockDim.x + threadIdx.x;
    int stride = gridDim.x * blockDim.x;
    float4* o4 = reinterpret_cast<float4*>(out);
    for (; i < nvec; i += stride) {
        float4 v = o4[i];
        float d = den[i >> 4];
        v.x /= d; v.y /= d; v.z /= d; v.w /= d;
        o4[i] = v;
    }
}

extern "C" void kernel_launch(void* const* d_in, const int* in_sizes, int n_in,
                              void* d_out, int out_size, void* d_ws, size_t ws_size,
                              hipStream_t stream)
{
    const float* emb = (const float*)d_in[0];   // (64,16)
    const float* cf  = (const float*)d_in[1];   // (E,16)
    const float* wts = (const float*)d_in[2];   // (E,)
    const int*   idx = (const int*)d_in[3];     // (E,)
    int E = in_sizes[2];
    float* out = (float*)d_out;

    // fast-path ws: cnt[NODES] | starts[NODES+1] | cur[NODES] | den[NODES] | pad | cfs[(E+32) rows]
    char* wsb = (char*)d_ws;
    int* cnt    = (int*)wsb;
    int* starts = cnt + NODES;
    int* cur    = starts + NODES + 1;
    float* den  = (float*)(cur + NODES);
    size_t off = (size_t)(4 * NODES + 1) * sizeof(int);
    off = (off + 255) & ~(size_t)255;
    float* cfs = (float*)(wsb + off);
    size_t need_big = off + ((size_t)E + 32) * 16 * sizeof(float);

    size_t need_csr = ((size_t)3 * NODES + 2 + 2 * (size_t)E) * sizeof(int);

    if (E < (1 << 26) && ws_size >= need_big) {
        hipMemsetAsync(cnt, 0, NODES * sizeof(int), stream);
        hipMemsetAsync(den, 0, NODES * sizeof(float), stream);
        count_node<<<2048, 256, 0, stream>>>(idx, cnt, E);
        scan4<<<1, 1024, 0, stream>>>(cnt, starts, cur, NODES);
        scatter_perm<<<4096, 256, 0, stream>>>(
            (const float4*)cf, wts, idx, cur, den, (float4*)cfs, E);
        gather_seg<<<2048, 256, 0, stream>>>(
            emb, (const float4*)cfs, starts, den, out);
    } else if (ws_size >= need_csr) {
        int* cnt2      = (int*)d_ws;
        int* starts2   = cnt2 + NODES;
        int* cursor2   = starts2 + NODES + 1;
        int* elist     = cursor2 + NODES;
        float* welist  = (float*)(elist + E);
        hipMemsetAsync(cnt2, 0, NODES * sizeof(int), stream);
        count_node<<<2048, 256, 0, stream>>>(idx, cnt2, E);
        scan4<<<1, 1024, 0, stream>>>(cnt2, starts2, cursor2, NODES);
        scatter_csr_fb<<<2048, 256, 0, stream>>>(idx, wts, cursor2, elist, welist, E);
        gather_csr_fb<<<4096, 256, 0, stream>>>(emb, cf, starts2, elist, welist, out);
    } else {
        float* den2 = (float*)d_ws;
        hipMemsetAsync(d_out, 0, (size_t)out_size * sizeof(float), stream);
        hipMemsetAsync(d_ws, 0, (size_t)NODES * sizeof(float), stream);
        edge_scatter_fb<<<4096, 256, 0, stream>>>(emb, cf, wts, idx, out, den2, E);
        divide_fb<<<2048, 256, 0, stream>>>(out, den2, out_size / 4);
    }
}

// Round 8
// 447.375 us; speedup vs baseline: 4.0782x; 1.3092x over previous
//
#include <hip/hip_runtime.h>
#include <cstddef>

constexpr int NODES = 100000;
constexpr int NPB   = 32;                      // nodes per bucket
constexpr int NBUCK = (NODES + NPB - 1) / NPB; // 3125
constexpr int NREP  = 8;                       // cursor replicas
constexpr int NFLAT = NBUCK * NREP;            // 25000
constexpr int CAP   = 2048;                    // max rows per bucket in LDS sort

typedef unsigned int uint;
typedef __attribute__((ext_vector_type(8)))  _Float16 f16x8;
typedef __attribute__((ext_vector_type(16))) float    f32x16;

__device__ __forceinline__ int rfl_i(int x) {
    return __builtin_amdgcn_readfirstlane(x);
}
__device__ __forceinline__ float rfl_f(float x) {
    return __int_as_float(__builtin_amdgcn_readfirstlane(__float_as_int(x)));
}
__device__ __forceinline__ uint pkh2(float a, float b) {
    union { uint u; _Float16 h[2]; } p;
    p.h[0] = (_Float16)a; p.h[1] = (_Float16)b;
    return p.u;
}

// ---- pass 1a: padded replicated bucket histogram ----
// edge->(wave,rep) mapping MUST match scatter_rows exactly.
__global__ __launch_bounds__(256) void count_pad(
    const int* __restrict__ idx, int* __restrict__ cntp, int E)
{
    const int rep = blockIdx.x & (NREP - 1);
    const int l = threadIdx.x & 63;
    const int g = l >> 1, q = l & 1;
    int wid = (blockIdx.x * blockDim.x + threadIdx.x) >> 6;
    int nw  = (gridDim.x * blockDim.x) >> 6;
    for (int base = wid * 32; base < E; base += nw * 32) {
        int e = base + g;
        if (e < E && q == 0) {
            int n = idx[e];
            atomicAdd(&cntp[(size_t)((n >> 5) * NREP + rep) * 32], 1);
        }
    }
}

// ---- pass 1b: compact padded counters + overflow check ----
__global__ __launch_bounds__(256) void compact_cnt(
    const int* __restrict__ cntp, int* __restrict__ cflat, int* __restrict__ flag)
{
    int i = blockIdx.x * blockDim.x + threadIdx.x;
    int stride = gridDim.x * blockDim.x;
    for (int j = i; j < NFLAT; j += stride) cflat[j] = cntp[(size_t)j * 32];
    for (int b = i; b < NBUCK; b += stride) {
        int t = 0;
        #pragma unroll
        for (int r = 0; r < NREP; ++r) t += cntp[(size_t)(b * NREP + r) * 32];
        if (t > CAP) *flag = 1;
    }
}

// ---- pass 2: single-block exclusive scan ----
__global__ __launch_bounds__(1024) void scan4(
    const int* __restrict__ cnt, int* __restrict__ starts, int* __restrict__ cur, int N)
{
    __shared__ int wsum[16];
    __shared__ int running_s;
    int tid = threadIdx.x, lane = tid & 63, wv = tid >> 6;
    if (tid == 0) running_s = 0;
    __syncthreads();
    for (int base = 0; base < N; base += 4096) {
        int i0 = base + tid * 4;
        int c0 = 0, c1 = 0, c2 = 0, c3 = 0;
        if (i0 + 3 < N) {
            int4 c = *(const int4*)(cnt + i0);
            c0 = c.x; c1 = c.y; c2 = c.z; c3 = c.w;
        } else {
            if (i0     < N) c0 = cnt[i0];
            if (i0 + 1 < N) c1 = cnt[i0 + 1];
            if (i0 + 2 < N) c2 = cnt[i0 + 2];
            if (i0 + 3 < N) c3 = cnt[i0 + 3];
        }
        int t = c0 + c1 + c2 + c3;
        int x = t;
        #pragma unroll
        for (int d = 1; d < 64; d <<= 1) {
            int v = __shfl_up(x, d);
            if (lane >= d) x += v;
        }
        if (lane == 63) wsum[wv] = x;
        __syncthreads();
        if (wv == 0 && lane < 16) {
            int y = wsum[lane];
            #pragma unroll
            for (int d = 1; d < 16; d <<= 1) {
                int v = __shfl_up(y, d);
                if (lane >= d) y += v;
            }
            wsum[lane] = y;
        }
        __syncthreads();
        int woff = (wv > 0) ? wsum[wv - 1] : 0;
        int r = running_s;
        int excl = r + woff + (x - t);
        int s0 = excl, s1 = excl + c0, s2 = s1 + c1, s3 = s2 + c2;
        if (i0     < N) { starts[i0]     = s0; cur[i0]     = s0; }
        if (i0 + 1 < N) { starts[i0 + 1] = s1; cur[i0 + 1] = s1; }
        if (i0 + 2 < N) { starts[i0 + 2] = s2; cur[i0 + 2] = s2; }
        if (i0 + 3 < N) { starts[i0 + 3] = s3; cur[i0 + 3] = s3; }
        int total = wsum[15];
        __syncthreads();
        if (tid == 0) running_s = r + total;
    }
    __syncthreads();
    if (tid == 0) starts[N] = running_s;
}

// ---- pass 2b: init padded cursors from flat starts ----
__global__ __launch_bounds__(256) void init_curs(
    const int* __restrict__ sflat, int* __restrict__ cursp)
{
    int i = blockIdx.x * blockDim.x + threadIdx.x;
    int stride = gridDim.x * blockDim.x;
    for (int j = i; j < NFLAT; j += stride) cursp[(size_t)j * 32] = sflat[j];
}

// ---- pass 3: scatter f16 premultiplied rows into bucket-replica regions ----
// 2 lanes per edge (16B halves); wtag = w with 5 mantissa LSBs = nloc.
__global__ __launch_bounds__(256) void scatter_rows(
    const float4* __restrict__ cf4, const float* __restrict__ wts,
    const int* __restrict__ idx, int* __restrict__ cursp,
    uint* __restrict__ wtag, uint4* __restrict__ rows, int E)
{
    const int rep = blockIdx.x & (NREP - 1);
    const int l = threadIdx.x & 63;
    const int g = l >> 1, q = l & 1;
    int wid = (blockIdx.x * blockDim.x + threadIdx.x) >> 6;
    int nw  = (gridDim.x * blockDim.x) >> 6;
    for (int base = wid * 32; base < E; base += nw * 32) {
        int e = base + g;
        bool valid = e < E;
        float4 c0, c1;
        float w = 0.f;
        int slot = 0;
        if (valid) {
            c0 = cf4[(size_t)e * 4 + q * 2];
            c1 = cf4[(size_t)e * 4 + q * 2 + 1];
            w  = wts[e];
            if (q == 0) {
                int n = idx[e];
                slot = atomicAdd(&cursp[(size_t)((n >> 5) * NREP + rep) * 32], 1);
                wtag[slot] = (__float_as_uint(w) & ~31u) | (uint)(n & 31);
            }
        }
        slot = __shfl(slot, l & ~1);
        if (valid) {
            uint4 o;
            o.x = pkh2(c0.x * w, c0.y * w);
            o.y = pkh2(c0.z * w, c0.w * w);
            o.z = pkh2(c1.x * w, c1.y * w);
            o.w = pkh2(c1.z * w, c1.w * w);
            rows[(size_t)slot * 2 + q] = o;
        }
    }
}

// ---- pass 4: per-bucket in-place node sort via LDS; emits per-node starts + den ----
__global__ __launch_bounds__(256) void bucket_sort(
    const int* __restrict__ sflat, const uint* __restrict__ wtag,
    uint4* __restrict__ rows, int* __restrict__ starts_n,
    float* __restrict__ den, const int* __restrict__ flag)
{
    if (*flag) return;
    __shared__ uint4  lrows[CAP * 2];     // 64 KB
    __shared__ uint   lwtag[CAP];         // 8 KB
    __shared__ unsigned short lperm[CAP]; // 4 KB
    __shared__ int   hist[NPB], lcur[NPB], lstart[NPB];
    __shared__ float lden[NPB];

    const int tid = threadIdx.x;
    const int b = blockIdx.x;
    const int rs = sflat[b * NREP];
    const int re = sflat[b * NREP + NREP];
    const int n = re - rs;

    if (tid < NPB) { hist[tid] = 0; lden[tid] = 0.f; }
    __syncthreads();
    if (n > CAP) return;   // flag already set by compact_cnt; fallback handles

    for (int i = tid; i < n; i += 256) {
        uint t = wtag[rs + i];
        lwtag[i] = t;
        int nl = (int)(t & 31u);
        float w = __uint_as_float(t & ~31u);
        atomicAdd(&hist[nl], 1);
        atomicAdd(&lden[nl], w);
        lrows[2 * i]     = rows[(size_t)(rs + i) * 2];
        lrows[2 * i + 1] = rows[(size_t)(rs + i) * 2 + 1];
    }
    __syncthreads();

    if (tid < NPB) {   // 32-lane exclusive scan
        int c = hist[tid];
        int x = c;
        #pragma unroll
        for (int d = 1; d < NPB; d <<= 1) {
            int v = __shfl_up(x, d);
            if (tid >= d) x += v;
        }
        lstart[tid] = x - c;
        lcur[tid]   = x - c;
        starts_n[b * NPB + tid] = rs + x - c;
        den[b * NPB + tid] = lden[tid];
        if (b == NBUCK - 1 && tid == 0) starts_n[NODES] = re;
    }
    __syncthreads();

    for (int i = tid; i < n; i += 256) {
        int nl = (int)(lwtag[i] & 31u);
        int d = atomicAdd(&lcur[nl], 1);
        lperm[d] = (unsigned short)i;
    }
    __syncthreads();

    for (int d = tid; d < n; d += 256) {
        int s = lperm[d];
        rows[(size_t)(rs + d) * 2]     = lrows[2 * s];
        rows[(size_t)(rs + d) * 2 + 1] = lrows[2 * s + 1];
    }
}

// ---- pass 5: per-node segment gather, MFMA, register reduce (R7-verified) ----
__global__ __launch_bounds__(256) void gather_seg(
    const float* __restrict__ emb, const uint4* __restrict__ rows,
    const int* __restrict__ starts, const float* __restrict__ den,
    float* __restrict__ out, const int* __restrict__ flag)
{
    if (*flag) return;
    const int l    = threadIdx.x & 63;
    const int ucol = l & 31;
    const int h    = l >> 5;

    f16x8 b0, b1;
    #pragma unroll
    for (int j = 0; j < 8; ++j) {
        b0[j] = (_Float16)emb[ucol * 16 + 8 * h + j];
        b1[j] = (_Float16)emb[(ucol + 32) * 16 + 8 * h + j];
    }

    f32x16 zacc;
    #pragma unroll
    for (int i = 0; i < 16; ++i) zacc[i] = 0.f;

    int gw = (blockIdx.x * blockDim.x + threadIdx.x) >> 6;
    int nw = (gridDim.x * blockDim.x) >> 6;

    for (int node = gw; node < NODES; node += nw) {
        int s = rfl_i(starts[node]);
        int e = rfl_i(starts[node + 1]);
        int cnt = e - s;
        float r0 = 0.f, r1 = 0.f;
        for (int ch = 0; ch < cnt; ch += 32) {
            int row = s + ch + ucol;
            bool valid = (ch + ucol) < cnt;
            uint4 v = rows[(size_t)row * 2 + h];   // 16B = the f16 A-fragment
            if (!valid) { v.x = 0; v.y = 0; v.z = 0; v.w = 0; }
            f16x8 a = *(f16x8*)&v;
            f32x16 d0 = __builtin_amdgcn_mfma_f32_32x32x16_f16(a, b0, zacc, 0, 0, 0);
            f32x16 d1 = __builtin_amdgcn_mfma_f32_32x32x16_f16(a, b1, zacc, 0, 0, 0);
            float t0 = 0.f, t1 = 0.f;
            #pragma unroll
            for (int r = 0; r < 16; ++r) {
                t0 += fmaxf(d0[r], 0.f);
                t1 += fmaxf(d1[r], 0.f);
            }
            r0 += t0; r1 += t1;
        }
        r0 += __shfl_xor(r0, 32);
        r1 += __shfl_xor(r1, 32);
        float d = rfl_f(den[node]);
        out[(size_t)node * 64 + l] = (h ? r1 : r0) / d;
    }
}

// ================= guarded fallbacks (no-op when flag==0 / null) =================

__global__ __launch_bounds__(256) void zero_fb(
    float* __restrict__ out, float* __restrict__ den, int nout,
    const int* __restrict__ flag)
{
    if (flag && !*flag) return;
    int i = blockIdx.x * blockDim.x + threadIdx.x;
    int stride = gridDim.x * blockDim.x;
    for (int j = i; j < nout; j += stride) out[j] = 0.f;
    for (int j = i; j < NODES; j += stride) den[j] = 0.f;
}

__global__ __launch_bounds__(256) void edge_scatter_fb(
    const float* __restrict__ emb, const float* __restrict__ cf,
    const float* __restrict__ wts, const int* __restrict__ idx,
    float* __restrict__ num, float* __restrict__ den, int E,
    const int* __restrict__ flag)
{
    if (flag && !*flag) return;
    const int lane = threadIdx.x & 63;
    float er[16];
    #pragma unroll
    for (int f = 0; f < 16; ++f) er[f] = emb[lane * 16 + f];
    int wid = rfl_i((int)((blockIdx.x * blockDim.x + threadIdx.x) >> 6));
    int nw = (gridDim.x * blockDim.x) >> 6;
    for (int e = wid; e < E; e += nw) {
        const float* c = cf + (size_t)e * 16;
        float a = 0.f;
        #pragma unroll
        for (int f = 0; f < 16; ++f) a = fmaf(c[f], er[f], a);
        float wv = wts[e];
        int n = idx[e];
        unsafeAtomicAdd(num + (size_t)n * 64 + lane, fmaxf(a, 0.f) * wv);
        if (lane == 0) unsafeAtomicAdd(den + n, wv);
    }
}

__global__ __launch_bounds__(256) void divide_fb(
    float* __restrict__ out, const float* __restrict__ den, int nvec,
    const int* __restrict__ flag)
{
    if (flag && !*flag) return;
    int i = blockIdx.x * blockDim.x + threadIdx.x;
    int stride = gridDim.x * blockDim.x;
    float4* o4 = reinterpret_cast<float4*>(out);
    for (; i < nvec; i += stride) {
        float4 v = o4[i];
        float d = den[i >> 4];
        v.x /= d; v.y /= d; v.z /= d; v.w /= d;
        o4[i] = v;
    }
}

extern "C" void kernel_launch(void* const* d_in, const int* in_sizes, int n_in,
                              void* d_out, int out_size, void* d_ws, size_t ws_size,
                              hipStream_t stream)
{
    const float* emb = (const float*)d_in[0];   // (64,16)
    const float* cf  = (const float*)d_in[1];   // (E,16)
    const float* wts = (const float*)d_in[2];   // (E,)
    const int*   idx = (const int*)d_in[3];     // (E,)
    int E = in_sizes[2];
    float* out = (float*)d_out;

    // ws layout
    char* p = (char*)d_ws;
    auto take = [&](size_t bytes) { char* r = p; p += (bytes + 255) & ~(size_t)255; return r; };
    int*  cntp     = (int*)take((size_t)NFLAT * 32 * sizeof(int));   // 3.2 MB padded
    int*  cursp    = (int*)take((size_t)NFLAT * 32 * sizeof(int));   // 3.2 MB padded
    int*  cflat    = (int*)take((size_t)NFLAT * sizeof(int));
    int*  sflat    = (int*)take((size_t)(NFLAT + 1) * sizeof(int));
    int*  starts_n = (int*)take((size_t)(NODES + 1) * sizeof(int));
    float* den     = (float*)take((size_t)NODES * sizeof(float));
    int*  flag     = (int*)take(256);
    uint* wtag     = (uint*)take((size_t)E * sizeof(uint));
    uint4* rows    = (uint4*)take(((size_t)E + 40) * 2 * sizeof(uint4)); // f16 rows + slack
    size_t need = (size_t)(p - (char*)d_ws);

    if (ws_size >= need) {
        hipMemsetAsync(cntp, 0, (size_t)NFLAT * 32 * sizeof(int), stream);
        hipMemsetAsync(flag, 0, sizeof(int), stream);
        count_pad<<<4096, 256, 0, stream>>>(idx, cntp, E);
        compact_cnt<<<128, 256, 0, stream>>>(cntp, cflat, flag);
        scan4<<<1, 1024, 0, stream>>>(cflat, sflat, sflat, NFLAT);
        init_curs<<<128, 256, 0, stream>>>(sflat, cursp);
        scatter_rows<<<4096, 256, 0, stream>>>(
            (const float4*)cf, wts, idx, cursp, wtag, rows, E);
        bucket_sort<<<NBUCK, 256, 0, stream>>>(sflat, wtag, rows, starts_n, den, flag);
        gather_seg<<<2048, 256, 0, stream>>>(emb, rows, starts_n, den, out, flag);
        // guarded fallback chain (no-ops when flag==0)
        zero_fb<<<2048, 256, 0, stream>>>(out, den, out_size, flag);
        edge_scatter_fb<<<4096, 256, 0, stream>>>(emb, cf, wts, idx, out, den, E, flag);
        divide_fb<<<2048, 256, 0, stream>>>(out, den, out_size / 4, flag);
    } else {
        // host fallback: plain atomic scatter (needs only NODES floats of ws)
        float* den2 = (float*)d_ws;
        hipMemsetAsync(d_out, 0, (size_t)out_size * sizeof(float), stream);
        hipMemsetAsync(d_ws, 0, (size_t)NODES * sizeof(float), stream);
        edge_scatter_fb<<<4096, 256, 0, stream>>>(emb, cf, wts, idx, out, den2, E, nullptr);
        divide_fb<<<2048, 256, 0, stream>>>(out, den2, out_size / 4, nullptr);
    }
}